// Round 1
// baseline (375.336 us; speedup 1.0000x reference)
//
#include <hip/hip_runtime.h>
#include <math.h>

// Kernel A: segment boundaries via binary search (ray_id is sorted).
// seg_start[r] = first index i with ray_id[i] >= r, for r in [0, N].
// seg_start[N] == M. Empty rays get seg_start[r] == seg_start[r+1].
__global__ void seg_starts_kernel(const int* __restrict__ ray_id, int M, int N,
                                  int* __restrict__ seg_start) {
    int r = blockIdx.x * blockDim.x + threadIdx.x;
    if (r > N) return;
    int lo = 0, hi = M;
    while (lo < hi) {
        int mid = (lo + hi) >> 1;
        if (ray_id[mid] < r) lo = mid + 1;
        else hi = mid;
    }
    seg_start[r] = lo;
}

// Kernel B: one wave (64 lanes) per ray.
// weights_i = alpha_i * exp(logT_i) = T_i - T_{i+1}, with
// t_i = exp(-interval * softplus(density_i + shift)) and T the running
// product of t. Wave does an inclusive product-scan per 64-sample chunk.
__launch_bounds__(256, 4)
__global__ void composite_kernel(const float* __restrict__ density,
                                 const float* __restrict__ rgb,
                                 const float* __restrict__ bg,
                                 const float* __restrict__ shift_p,
                                 const float* __restrict__ interval_p,
                                 const int* __restrict__ seg_start,
                                 float* __restrict__ out, int N) {
    const int wave = threadIdx.x >> 6;
    const int lane = threadIdx.x & 63;
    const int r = blockIdx.x * (blockDim.x >> 6) + wave;
    if (r >= N) return;

    const float shift = *shift_p;
    const float interval = *interval_p;
    const int s = seg_start[r];
    const int e = seg_start[r + 1];

    float T = 1.0f;                 // running transmittance (wave-uniform)
    float ar = 0.f, ag = 0.f, ab = 0.f;

    for (int base = s; base < e; base += 64) {
        int i = base + lane;
        float t1 = 1.0f;            // identity for masked lanes
        float cr = 0.f, cg = 0.f, cb = 0.f;
        if (i < e) {
            float x = density[i] + shift;
            // softplus, overflow-safe: for x>20, log1p(exp(x)) == x to fp32
            float sp = (x > 20.0f) ? x : log1pf(__expf(x));
            t1 = __expf(-interval * sp);
            cr = rgb[3 * i + 0];
            cg = rgb[3 * i + 1];
            cb = rgb[3 * i + 2];
        }
        // inclusive product scan across the wave
        float p = t1;
        #pragma unroll
        for (int off = 1; off < 64; off <<= 1) {
            float o = __shfl_up(p, off);
            if (lane >= off) p *= o;
        }
        // exclusive prefix (T_i / T), weight = T*(excl - incl) = T_i - T_{i+1}
        float excl = __shfl_up(p, 1);
        if (lane == 0) excl = 1.0f;
        float w = T * (excl - p);
        ar += w * cr;
        ag += w * cg;
        ab += w * cb;
        // carry full-chunk product into next chunk
        T *= __shfl(p, 63);
    }

    // wave reduction of the rgb accumulators
    #pragma unroll
    for (int off = 32; off > 0; off >>= 1) {
        ar += __shfl_xor(ar, off);
        ag += __shfl_xor(ag, off);
        ab += __shfl_xor(ab, off);
    }

    if (lane == 0) {
        out[3 * r + 0] = ar + T * bg[0];
        out[3 * r + 1] = ag + T * bg[1];
        out[3 * r + 2] = ab + T * bg[2];
    }
}

extern "C" void kernel_launch(void* const* d_in, const int* in_sizes, int n_in,
                              void* d_out, int out_size, void* d_ws, size_t ws_size,
                              hipStream_t stream) {
    const float* density  = (const float*)d_in[0];
    const float* rgb      = (const float*)d_in[1];
    const float* bg       = (const float*)d_in[2];
    const float* shift    = (const float*)d_in[3];
    const float* interval = (const float*)d_in[4];
    const int*   ray_id   = (const int*)d_in[5];

    const int M = in_sizes[0];       // samples
    const int N = out_size / 3;      // rays

    int* seg_start = (int*)d_ws;     // N+1 ints

    {
        int threads = 256;
        int blocks = (N + 1 + threads - 1) / threads;
        seg_starts_kernel<<<blocks, threads, 0, stream>>>(ray_id, M, N, seg_start);
    }
    {
        const int wavesPerBlock = 4;  // 256 threads
        int blocks = (N + wavesPerBlock - 1) / wavesPerBlock;
        composite_kernel<<<blocks, 256, 0, stream>>>(density, rgb, bg, shift,
                                                     interval, seg_start,
                                                     (float*)d_out, N);
    }
}

// Round 2
// 341.020 us; speedup vs baseline: 1.1006x; 1.1006x over previous
//
#include <hip/hip_runtime.h>
#include <math.h>

// Kernel A: segment boundaries via binary search (ray_id is sorted).
// seg_start[r] = first index i with ray_id[i] >= r, for r in [0, N].
__global__ void seg_starts_kernel(const int* __restrict__ ray_id, int M, int N,
                                  int* __restrict__ seg_start) {
    int r = blockIdx.x * blockDim.x + threadIdx.x;
    if (r > N) return;
    int lo = 0, hi = M;
    while (lo < hi) {
        int mid = (lo + hi) >> 1;
        if (ray_id[mid] < r) lo = mid + 1;
        else hi = mid;
    }
    seg_start[r] = lo;
}

__device__ __forceinline__ float transmit(float d, float shift, float interval) {
    float x = d + shift;
    // softplus, overflow-safe: for x>20, log1p(exp(x)) == x to fp32
    float sp = (x > 20.0f) ? x : log1pf(__expf(x));
    return __expf(-interval * sp);
}

// Kernel B: one wave per ray, 2 samples per lane (128-sample chunks).
// weights_i = T_i - T_{i+1}; T = running product of per-sample transmittance.
// Early exit when wave-uniform T < 1e-9: remaining weights sum to <= T, and
// the bg term changes by <= T -- error <= 1e-9 per channel vs 1.78e-2 thresh.
__launch_bounds__(256, 4)
__global__ void composite_kernel(const float* __restrict__ density,
                                 const float* __restrict__ rgb,
                                 const float* __restrict__ bg,
                                 const float* __restrict__ shift_p,
                                 const float* __restrict__ interval_p,
                                 const int* __restrict__ seg_start,
                                 float* __restrict__ out, int N) {
    const int wave = threadIdx.x >> 6;
    const int lane = threadIdx.x & 63;
    const int r = blockIdx.x * (blockDim.x >> 6) + wave;
    if (r >= N) return;

    const float shift = *shift_p;
    const float interval = *interval_p;
    const int s = seg_start[r];
    const int e = seg_start[r + 1];

    float T = 1.0f;                 // running transmittance (wave-uniform)
    float ar = 0.f, ag = 0.f, ab = 0.f;

    // Align chunk base to an even sample so float2 loads are 8B-aligned
    // (density: 8*j0/2 bytes; rgb: 12*j0 = 24m bytes -- both 8B-aligned).
    for (int base = (s & ~1); base < e; base += 128) {
        int j0 = base + 2 * lane;
        float t0 = 1.f, t1 = 1.f;
        float r0 = 0.f, g0 = 0.f, b0 = 0.f, r1 = 0.f, g1 = 0.f, b1 = 0.f;

        if (j0 >= s && j0 + 1 < e) {
            // fast path: both samples valid, vector loads
            float2 d2 = *(const float2*)(density + j0);
            t0 = transmit(d2.x, shift, interval);
            t1 = transmit(d2.y, shift, interval);
            const float2* rg = (const float2*)(rgb + 3 * j0);
            float2 p0 = rg[0], p1 = rg[1], p2 = rg[2];
            r0 = p0.x; g0 = p0.y; b0 = p1.x;
            r1 = p1.y; g1 = p2.x; b1 = p2.y;
        } else {
            // edge lanes (segment head/tail): scalar masked path
            if (j0 >= s && j0 < e) {
                t0 = transmit(density[j0], shift, interval);
                r0 = rgb[3 * j0 + 0]; g0 = rgb[3 * j0 + 1]; b0 = rgb[3 * j0 + 2];
            }
            int j1 = j0 + 1;
            if (j1 >= s && j1 < e) {
                t1 = transmit(density[j1], shift, interval);
                r1 = rgb[3 * j1 + 0]; g1 = rgb[3 * j1 + 1]; b1 = rgb[3 * j1 + 2];
            }
        }

        float q = t0 * t1;          // lane-local product
        // inclusive product scan of q across the wave
        float p = q;
        #pragma unroll
        for (int off = 1; off < 64; off <<= 1) {
            float o = __shfl_up(p, off);
            if (lane >= off) p *= o;
        }
        float excl = __shfl_up(p, 1);
        if (lane == 0) excl = 1.0f;
        float Tl = T * excl;        // transmittance entering this lane
        // w0 = Tl*(1-t0), w1 = Tl*(t0 - t0*t1)
        ar += Tl * ((1.f - t0) * r0 + (t0 - q) * r1);
        ag += Tl * ((1.f - t0) * g0 + (t0 - q) * g1);
        ab += Tl * ((1.f - t0) * b0 + (t0 - q) * b1);

        T *= __shfl(p, 63);         // carry chunk product (wave-uniform)
        if (T < 1e-9f) break;       // uniform branch: tail contributes < 1e-9
    }

    // wave reduction of the rgb accumulators
    #pragma unroll
    for (int off = 32; off > 0; off >>= 1) {
        ar += __shfl_xor(ar, off);
        ag += __shfl_xor(ag, off);
        ab += __shfl_xor(ab, off);
    }

    if (lane == 0) {
        out[3 * r + 0] = ar + T * bg[0];
        out[3 * r + 1] = ag + T * bg[1];
        out[3 * r + 2] = ab + T * bg[2];
    }
}

extern "C" void kernel_launch(void* const* d_in, const int* in_sizes, int n_in,
                              void* d_out, int out_size, void* d_ws, size_t ws_size,
                              hipStream_t stream) {
    const float* density  = (const float*)d_in[0];
    const float* rgb      = (const float*)d_in[1];
    const float* bg       = (const float*)d_in[2];
    const float* shift    = (const float*)d_in[3];
    const float* interval = (const float*)d_in[4];
    const int*   ray_id   = (const int*)d_in[5];

    const int M = in_sizes[0];       // samples
    const int N = out_size / 3;      // rays

    int* seg_start = (int*)d_ws;     // N+1 ints

    {
        int threads = 256;
        int blocks = (N + 1 + threads - 1) / threads;
        seg_starts_kernel<<<blocks, threads, 0, stream>>>(ray_id, M, N, seg_start);
    }
    {
        const int wavesPerBlock = 4;  // 256 threads
        int blocks = (N + wavesPerBlock - 1) / wavesPerBlock;
        composite_kernel<<<blocks, 256, 0, stream>>>(density, rgb, bg, shift,
                                                     interval, seg_start,
                                                     (float*)d_out, N);
    }
}

// Round 3
// 326.694 us; speedup vs baseline: 1.1489x; 1.0439x over previous
//
#include <hip/hip_runtime.h>
#include <math.h>

// Kernel A: segment boundaries via binary search (ray_id is sorted).
// seg_start[r] = first index i with ray_id[i] >= r, for r in [0, N].
// 1024 waves, one 24-deep dependent-gather chain each -- cheap (~5 us).
__global__ void seg_starts_kernel(const int* __restrict__ ray_id, int M, int N,
                                  int* __restrict__ seg_start) {
    int r = blockIdx.x * blockDim.x + threadIdx.x;
    if (r > N) return;
    int lo = 0, hi = M;
    while (lo < hi) {
        int mid = (lo + hi) >> 1;
        if (ray_id[mid] < r) lo = mid + 1;
        else hi = mid;
    }
    seg_start[r] = lo;
}

// Kernel B: one wave per ray, 1 sample/lane, 64-sample chunks.
// t_i = (1+exp(d+shift))^(-interval) = exp2(-interval*log2(1+exp(x)))
//   == reference (1-alpha) exactly; limits: x>>0 -> t=0, x<<0 -> t=1.
// weights_i = T_i - T_{i+1} via wave inclusive-product scan.
// Early exit when wave-uniform T < 1e-5: dropped tail + bg perturbation
// bound output error by 2e-5 << 1.78e-2 threshold. 64-sample granularity
// lets ~89% of rays stop after one chunk (~73 samples/ray avg).
__launch_bounds__(256, 8)
__global__ void composite_kernel(const float* __restrict__ density,
                                 const float* __restrict__ rgb,
                                 const float* __restrict__ bg,
                                 const float* __restrict__ shift_p,
                                 const float* __restrict__ interval_p,
                                 const int* __restrict__ seg_start,
                                 float* __restrict__ out, int N, int M) {
    const int wave = threadIdx.x >> 6;
    const int lane = threadIdx.x & 63;
    const int r = blockIdx.x * (blockDim.x >> 6) + wave;
    if (r >= N) return;

    const float shift = *shift_p;
    const float nI = -(*interval_p);
    const int s = seg_start[r];
    const int e = seg_start[r + 1];

    float T = 1.0f;                 // running transmittance (wave-uniform)
    float ar = 0.f, ag = 0.f, ab = 0.f;

    for (int base = s; base < e; base += 64) {
        int i = base + lane;
        int ic = (i < M - 1) ? i : (M - 1);   // clamp: loads stay in-bounds
        float d  = density[ic];
        float cr = rgb[3 * ic + 0];
        float cg = rgb[3 * ic + 1];
        float cb = rgb[3 * ic + 2];
        // branch-free transmittance; masked (i>=e) lanes forced to t=1
        float t = exp2f(nI * __log2f(1.0f + __expf(d + shift)));
        t = (i < e) ? t : 1.0f;

        // inclusive product scan across the wave
        float p = t;
        #pragma unroll
        for (int off = 1; off < 64; off <<= 1) {
            float o = __shfl_up(p, off);
            p *= (lane >= off) ? o : 1.0f;
        }
        float excl = __shfl_up(p, 1);
        if (lane == 0) excl = 1.0f;
        float w = T * (excl - p);   // = T_i - T_{i+1}; exactly 0 on masked lanes
        ar += w * cr;
        ag += w * cg;
        ab += w * cb;

        T *= __shfl(p, 63);         // carry chunk product (wave-uniform)
        if (T < 1e-5f) break;       // uniform branch; error bound 2e-5
    }

    // wave reduction of the rgb accumulators
    #pragma unroll
    for (int off = 32; off > 0; off >>= 1) {
        ar += __shfl_xor(ar, off);
        ag += __shfl_xor(ag, off);
        ab += __shfl_xor(ab, off);
    }

    if (lane == 0) {
        out[3 * r + 0] = ar + T * bg[0];
        out[3 * r + 1] = ag + T * bg[1];
        out[3 * r + 2] = ab + T * bg[2];
    }
}

extern "C" void kernel_launch(void* const* d_in, const int* in_sizes, int n_in,
                              void* d_out, int out_size, void* d_ws, size_t ws_size,
                              hipStream_t stream) {
    const float* density  = (const float*)d_in[0];
    const float* rgb      = (const float*)d_in[1];
    const float* bg       = (const float*)d_in[2];
    const float* shift    = (const float*)d_in[3];
    const float* interval = (const float*)d_in[4];
    const int*   ray_id   = (const int*)d_in[5];

    const int M = in_sizes[0];       // samples
    const int N = out_size / 3;      // rays

    int* seg_start = (int*)d_ws;     // N+1 ints

    {
        int threads = 256;
        int blocks = (N + 1 + threads - 1) / threads;
        seg_starts_kernel<<<blocks, threads, 0, stream>>>(ray_id, M, N, seg_start);
    }
    {
        const int wavesPerBlock = 4;  // 256 threads
        int blocks = (N + wavesPerBlock - 1) / wavesPerBlock;
        composite_kernel<<<blocks, 256, 0, stream>>>(density, rgb, bg, shift,
                                                     interval, seg_start,
                                                     (float*)d_out, N, M);
    }
}

// Round 4
// 325.242 us; speedup vs baseline: 1.1540x; 1.0045x over previous
//
#include <hip/hip_runtime.h>
#include <math.h>

// Kernel A: segment boundaries via binary search (ray_id is sorted).
// seg_start[r] = first index i with ray_id[i] >= r, for r in [0, N].
__global__ void seg_starts_kernel(const int* __restrict__ ray_id, int M, int N,
                                  int* __restrict__ seg_start) {
    int r = blockIdx.x * blockDim.x + threadIdx.x;
    if (r > N) return;
    int lo = 0, hi = M;
    while (lo < hi) {
        int mid = (lo + hi) >> 1;
        if (ray_id[mid] < r) lo = mid + 1;
        else hi = mid;
    }
    seg_start[r] = lo;
}

// Kernel B: TWO rays per wave -- lanes 0-31 handle ray 2w, lanes 32-63 ray
// 2w+1. 32-sample chunks per ray via width=32 segmented product scan.
// t_i = (1+exp(d+shift))^(-interval) == reference (1-alpha) exactly.
// weights_i = T_i - T_{i+1}. Per-half early exit at T < 1e-3: dropped tail
// + bg perturbation bound the output error by 2e-3 (<< 1.78e-2 threshold).
// A finished half freezes its base (clamped reloads hit L1, t=1 -> w=0);
// the wave loop exits when both halves are done.
__launch_bounds__(256, 8)
__global__ void composite_kernel(const float* __restrict__ density,
                                 const float* __restrict__ rgb,
                                 const float* __restrict__ bg,
                                 const float* __restrict__ shift_p,
                                 const float* __restrict__ interval_p,
                                 const int* __restrict__ seg_start,
                                 float* __restrict__ out, int N, int M) {
    const int wave = threadIdx.x >> 6;
    const int lane = threadIdx.x & 63;
    const int sl   = lane & 31;           // sub-lane within half
    const int half = lane >> 5;
    const int w    = blockIdx.x * (blockDim.x >> 6) + wave;
    const int ray  = 2 * w + half;        // this half's ray

    const float shift = *shift_p;
    const float nI = -(*interval_p);

    int s = 0, e = 0;
    if (ray < N) { s = seg_start[ray]; e = seg_start[ray + 1]; }

    float T = 1.0f;                       // running transmittance (half-uniform)
    float ar = 0.f, ag = 0.f, ab = 0.f;
    int  base   = s;
    bool active = (base < e);

    while (__ballot(active)) {
        int i = base + sl;
        bool valid = active && (i < e);
        int ic = (i < M - 1) ? i : (M - 1);         // in-bounds, coalesced
        float d  = density[ic];
        float cr = rgb[3 * ic + 0];
        float cg = rgb[3 * ic + 1];
        float cb = rgb[3 * ic + 2];
        // branch-free transmittance; invalid lanes forced to identity t=1
        float t = exp2f(nI * __log2f(1.0f + __expf(d + shift)));
        t = valid ? t : 1.0f;

        // inclusive product scan within the 32-lane half
        float p = t;
        #pragma unroll
        for (int off = 1; off < 32; off <<= 1) {
            float o = __shfl_up(p, off, 32);
            p *= (sl >= off) ? o : 1.0f;
        }
        float excl = __shfl_up(p, 1, 32);
        if (sl == 0) excl = 1.0f;
        float wgt = T * (excl - p);       // = T_i - T_{i+1}; 0 on invalid lanes
        ar += wgt * cr;
        ag += wgt * cg;
        ab += wgt * cb;

        float chunk = __shfl(p, 31, 32);  // half-uniform chunk product
        if (active) {
            T *= chunk;
            base += 32;
            active = (base < e) && (T >= 1e-3f);
        }
    }

    // rgb reduction within each 32-lane half
    #pragma unroll
    for (int off = 16; off > 0; off >>= 1) {
        ar += __shfl_xor(ar, off, 32);
        ag += __shfl_xor(ag, off, 32);
        ab += __shfl_xor(ab, off, 32);
    }

    if (sl == 0 && ray < N) {
        out[3 * ray + 0] = ar + T * bg[0];
        out[3 * ray + 1] = ag + T * bg[1];
        out[3 * ray + 2] = ab + T * bg[2];
    }
}

extern "C" void kernel_launch(void* const* d_in, const int* in_sizes, int n_in,
                              void* d_out, int out_size, void* d_ws, size_t ws_size,
                              hipStream_t stream) {
    const float* density  = (const float*)d_in[0];
    const float* rgb      = (const float*)d_in[1];
    const float* bg       = (const float*)d_in[2];
    const float* shift    = (const float*)d_in[3];
    const float* interval = (const float*)d_in[4];
    const int*   ray_id   = (const int*)d_in[5];

    const int M = in_sizes[0];       // samples
    const int N = out_size / 3;      // rays

    int* seg_start = (int*)d_ws;     // N+1 ints

    {
        int threads = 256;
        int blocks = (N + 1 + threads - 1) / threads;
        seg_starts_kernel<<<blocks, threads, 0, stream>>>(ray_id, M, N, seg_start);
    }
    {
        // 4 waves/block, 2 rays/wave -> 8 rays per block
        int raysPerBlock = 8;
        int blocks = (N + raysPerBlock - 1) / raysPerBlock;
        composite_kernel<<<blocks, 256, 0, stream>>>(density, rgb, bg, shift,
                                                     interval, seg_start,
                                                     (float*)d_out, N, M);
    }
}